// Round 1
// baseline (155.479 us; speedup 1.0000x reference)
//
#include <hip/hip_runtime.h>
#include <hip/hip_bf16.h>
#include <stdint.h>

#define T_SEQ 4096

typedef float  f32x4   __attribute__((ext_vector_type(4)));
typedef float  f32x16  __attribute__((ext_vector_type(16)));
typedef short  bf16x8  __attribute__((ext_vector_type(8)));
typedef unsigned int u32x2 __attribute__((ext_vector_type(2)));
typedef unsigned int u32x4 __attribute__((ext_vector_type(4)));

typedef const __attribute__((address_space(1))) uint32_t* gptr_t;
typedef __attribute__((address_space(3))) uint32_t* lptr_t;

__device__ __forceinline__ uint32_t f2bf1(float f) {
    uint32_t u = __float_as_uint(f);
    return (u + 0x7fffu + ((u >> 16) & 1u)) >> 16;   // RNE f32->bf16
}
__device__ __forceinline__ short f2bfs(float f) { return (short)f2bf1(f); }
__device__ __forceinline__ uint32_t cvtpk(float lo, float hi) {
    uint32_t r;
    asm("v_cvt_pk_bf16_f32 %0, %1, %2" : "=v"(r) : "v"(lo), "v"(hi));
    return r;
}

// ---------------------------------------------------------------------------
// Kernel 1: Q,K projections. Q pre-scaled by 0.125*log2(e) (softmax uses 2^x).
// Layout: [bh=b*2+h][t][64] bf16.
// ---------------------------------------------------------------------------
__global__ __launch_bounds__(256) void qk_proj(
    const float* __restrict__ x,
    const float* __restrict__ Wq1, const float* __restrict__ Wk1,
    const float* __restrict__ Wq2, const float* __restrict__ Wk2,
    short* __restrict__ Q, short* __restrict__ K)
{
    int idx = blockIdx.x * 256 + threadIdx.x;
    int d = idx & 63;
    int t = (idx >> 6) & (T_SEQ - 1);
    int b = idx >> 18;
    const float* xp = x + (size_t)(b * T_SEQ + t) * 6;
    float x0 = xp[0], x1 = xp[1], x2 = xp[2];
    float x3 = xp[3], x4 = xp[4], x5 = xp[5];
    const float QS = 0.125f * 1.44269504088896340736f;
    float q1 = (x0 * Wq1[d] + x1 * Wq1[64 + d] + x2 * Wq1[128 + d]) * QS;
    float k1 =  x0 * Wk1[d] + x1 * Wk1[64 + d] + x2 * Wk1[128 + d];
    float q2 = (x3 * Wq2[d] + x4 * Wq2[64 + d] + x5 * Wq2[128 + d]) * QS;
    float k2 =  x3 * Wk2[d] + x4 * Wk2[64 + d] + x5 * Wk2[128 + d];
    size_t base1 = ((size_t)(b * 2 + 0) * T_SEQ + t) * 64 + d;
    size_t base2 = ((size_t)(b * 2 + 1) * T_SEQ + t) * 64 + d;
    Q[base1] = f2bfs(q1);  Q[base2] = f2bfs(q2);
    K[base1] = f2bfs(k1);  K[base2] = f2bfs(k2);
}

// ---------------------------------------------------------------------------
// Kernel 2: V projection written TRANSPOSED: Vt[bh][d][t] bf16.
// ---------------------------------------------------------------------------
__global__ __launch_bounds__(256) void v_proj_t(
    const float* __restrict__ x,
    const float* __restrict__ Wv1, const float* __restrict__ Wv2,
    short* __restrict__ Vt)
{
    int bh = blockIdx.x >> 6;
    int tt = blockIdx.x & 63;
    int head = bh & 1, b = bh >> 1;
    int t  = tt * 64 + (threadIdx.x & 63);
    int dg = threadIdx.x >> 6;
    const float* Wv = head ? Wv2 : Wv1;
    const float* xp = x + (size_t)(b * T_SEQ + t) * 6 + head * 3;
    float x0 = xp[0], x1 = xp[1], x2 = xp[2];
    size_t base = (size_t)bh * 64 * T_SEQ + t;
    #pragma unroll
    for (int k = 0; k < 16; ++k) {
        int d = dg * 16 + k;
        float v = x0 * Wv[d] + x1 * Wv[64 + d] + x2 * Wv[128 + d];
        Vt[base + (size_t)d * T_SEQ] = f2bfs(v);
    }
}

// ---------------------------------------------------------------------------
// Kernel 3: causal flash attention, FOLDED + intra-block kv-3-split.
//   R1 restructure: 192-thread blocks (3 waves), chunk = 96 kv, wave W owns
//   kv slice [kv0+32W, +31] of each chunk for BOTH fold tiles (A=i, B=127-i).
//   Occupancy: grid 1024 all-resident at 4 blocks/CU = 12 waves/CU (3/SIMD,
//   within the ~160-reg acc+qf budget) vs prior 8 waves/CU -- the kernel is
//   latency-bound (MfmaUtil 18 / VALUBusy 40 / Occ 18), so waves are the lever.
//   LDS: K only (96x128B, dbuf 24KB) so 4 blocks fit; V fragments are loaded
//   DIRECTLY from global (L1/L2-resident; vf00/01 + h pairs cover full 64B
//   lines) -- removes V ds_reads (bank conflicts) and halves global_load_lds.
//   V loads issue BEFORE the stage so PV's vmcnt wait leaves prefetch in
//   flight. OOB guard: last chunk (43*96>4096) clamps stage rows / V base;
//   those elements are causal-masked anyway.
//   MASK RULE: mask needed iff max_kv (kv0+32W+31) > MIN q of tile (t0X).
//   Combine: 3 partials/tile via 2-round LDS tree, stride 33 f32 (33*4B ->
//   bank = lane+4g mod 32: conflict-free; old 36-stride was 8-way).
// ---------------------------------------------------------------------------
__global__ __launch_bounds__(192, 3) void attn(
    const short* __restrict__ Q, const short* __restrict__ K,
    const short* __restrict__ Vt, float* __restrict__ Hf)
{
    __shared__ __align__(16) char smem[24576];  // dbuf 2 x 12KB (K only)

    int id = blockIdx.x;
    int xcd = id & 7, j = id >> 3;       // j 0..127
    int bh = xcd * 2 + (j & 1);          // 2 bh per XCD (L2 locality)
    int i  = j >> 1;                     // fold index 0..63
    int tid = threadIdx.x;
    int W = tid >> 6;                    // wave = kv-third (0..2)
    int lane = tid & 63;
    int ql = lane & 31, h = lane >> 5;
    int t0A = 32 * i, t0B = 32 * (127 - i);
    int qA = t0A + ql, qB = t0B + ql;
    int sweep = (t0B + 31) / 96 + 1;     // 96-kv chunks for tile B extent

    size_t kvbase = (size_t)bh * (T_SEQ * 64);

    // Q fragments for both tiles (B-operand): lane holds Q[q][ks*16+h*8+j]
    bf16x8 qfA[4], qfB[4];
    #pragma unroll
    for (int ks = 0; ks < 4; ++ks) {
        qfA[ks] = *(const bf16x8*)(Q + kvbase + (size_t)qA * 64 + ks * 16 + h * 8);
        qfB[ks] = *(const bf16x8*)(Q + kvbase + (size_t)qB * 64 + ks * 16 + h * 8);
    }

    // K staging constants (192 threads): r24 = tid>>3 (0..23), slot = tid&7,
    // pre-swizzled source column; LDS dest linear (T2: swizzle on read).
    // Per z: 24 rows; 24 % 8 == 0 so (z*24+r24)&7 == r24&7 (swizzle parity ok).
    int r24 = tid >> 3;
    int scol = ((tid & 7) ^ (r24 & 7)) * 8;
    const short* ksrc0 = K + kvbase + scol;

    // V direct-from-global row pointers (d = ql and d = 32+ql)
    const short* vrow0 = Vt + kvbase + (size_t)ql * T_SEQ;
    const short* vrow1 = vrow0 + (size_t)32 * T_SEQ;

    f32x16 accA0, accA1, accB0, accB1;
    #pragma unroll
    for (int r = 0; r < 16; ++r) { accA0[r]=0.f; accA1[r]=0.f; accB0[r]=0.f; accB1[r]=0.f; }
    float lA = 0.f, lB = 0.f;

#define STAGE(nb, kvv)                                                          \
    _Pragma("unroll")                                                           \
    for (int z = 0; z < 4; ++z) {                                               \
        int srow = (kvv) + z * 24 + r24;                                        \
        srow = srow > (T_SEQ - 1) ? (T_SEQ - 1) : srow;                         \
        __builtin_amdgcn_global_load_lds(                                       \
            (gptr_t)(ksrc0 + (size_t)srow * 64),                                \
            (lptr_t)((nb) + z * 3072 + W * 1024), 16, 0, 0);                    \
    }

    STAGE(smem, 0);                      // prologue: chunk 0 -> buf 0
    __syncthreads();

    int swz = (ql & 7) << 4;

    for (int c = 0; c < sweep; ++c) {
        const int kv0 = 96 * c;

        // V fragments (direct global) -- issue BEFORE stage so the PV wait is
        // a counted vmcnt, leaving next-chunk K prefetch in flight.
        int kvw = kv0 + 32 * W + 8 * h;
        int kvc = kvw > (T_SEQ - 24) ? (T_SEQ - 24) : kvw;   // OOB clamp (masked)
        bf16x8 vf00 = *(const bf16x8*)(vrow0 + kvc);
        bf16x8 vf01 = *(const bf16x8*)(vrow0 + kvc + 16);
        bf16x8 vf10 = *(const bf16x8*)(vrow1 + kvc);
        bf16x8 vf11 = *(const bf16x8*)(vrow1 + kvc + 16);

        if (c + 1 < sweep) { char* nb = smem + ((c + 1) & 1) * 12288; STAGE(nb, kv0 + 96); }
        const char* ldsK = smem + (c & 1) * 12288;

        bool actA = (kv0 + 32 * W <= t0A + 31);
        bool actB = (kv0 + 32 * W <= t0B + 31);

        // K fragments for this wave's kv-third (shared by tiles A and B)
        const char* krow = ldsK + (32 * W + ql) * 128;
        bf16x8 kf0 = *(const bf16x8*)(krow + ((0 * 32 + h * 16) ^ swz));
        bf16x8 kf1 = *(const bf16x8*)(krow + ((1 * 32 + h * 16) ^ swz));
        bf16x8 kf2 = *(const bf16x8*)(krow + ((2 * 32 + h * 16) ^ swz));
        bf16x8 kf3 = *(const bf16x8*)(krow + ((3 * 32 + h * 16) ^ swz));

        bf16x8 pfA0, pfA1, pfB0, pfB1;

#define QK_SM(qfX, qX, lX, pf0, pf1)                                            \
        {                                                                       \
            f32x16 Sv;                                                          \
            _Pragma("unroll") for (int r = 0; r < 16; ++r) Sv[r] = 0.f;         \
            Sv = __builtin_amdgcn_mfma_f32_32x32x16_bf16(kf0, qfX[0], Sv,0,0,0);\
            Sv = __builtin_amdgcn_mfma_f32_32x32x16_bf16(kf1, qfX[1], Sv,0,0,0);\
            Sv = __builtin_amdgcn_mfma_f32_32x32x16_bf16(kf2, qfX[2], Sv,0,0,0);\
            Sv = __builtin_amdgcn_mfma_f32_32x32x16_bf16(kf3, qfX[3], Sv,0,0,0);\
            bool needmask = (kv0 + 32 * W + 31 > (qX) - ql);  /* max_kv>t0X */  \
            uint32_t pw[8];                                                     \
            float l0 = 0.f, l1 = 0.f;                                           \
            _Pragma("unroll") for (int e = 0; e < 8; ++e) {                     \
                float p0 = __builtin_amdgcn_exp2f(Sv[2 * e]);                   \
                float p1 = __builtin_amdgcn_exp2f(Sv[2 * e + 1]);               \
                if (needmask) {                                                 \
                    int kv = kv0 + 32 * W + 4 * h + 2 * (e & 1) + 8 * (e >> 1); \
                    p0 = (kv     <= (qX)) ? p0 : 0.f;                           \
                    p1 = (kv + 1 <= (qX)) ? p1 : 0.f;                           \
                }                                                               \
                l0 += p0; l1 += p1;                                             \
                pw[e] = cvtpk(p0, p1);                                          \
            }                                                                   \
            lX += l0 + l1;                                                      \
            {                                                                   \
                uint32_t a0 = pw[0], b0 = pw[2], a1 = pw[1], b1 = pw[3];        \
                asm("v_permlane32_swap_b32 %0, %1" : "+v"(a0), "+v"(b0));       \
                asm("v_permlane32_swap_b32 %0, %1" : "+v"(a1), "+v"(b1));       \
                u32x4 fr = {a0, a1, b0, b1};                                    \
                pf0 = __builtin_bit_cast(bf16x8, fr);                           \
                uint32_t c0 = pw[4], d0 = pw[6], c1 = pw[5], d1 = pw[7];        \
                asm("v_permlane32_swap_b32 %0, %1" : "+v"(c0), "+v"(d0));       \
                asm("v_permlane32_swap_b32 %0, %1" : "+v"(c1), "+v"(d1));       \
                u32x4 fr1 = {c0, c1, d0, d1};                                   \
                pf1 = __builtin_bit_cast(bf16x8, fr1);                          \
            }                                                                   \
        }

        if (actB) QK_SM(qfB, qB, lB, pfB0, pfB1)
        if (actA) QK_SM(qfA, qA, lA, pfA0, pfA1)

        if (actB) {
            accB0 = __builtin_amdgcn_mfma_f32_32x32x16_bf16(vf00, pfB0, accB0, 0, 0, 0);
            accB0 = __builtin_amdgcn_mfma_f32_32x32x16_bf16(vf01, pfB1, accB0, 0, 0, 0);
            accB1 = __builtin_amdgcn_mfma_f32_32x32x16_bf16(vf10, pfB0, accB1, 0, 0, 0);
            accB1 = __builtin_amdgcn_mfma_f32_32x32x16_bf16(vf11, pfB1, accB1, 0, 0, 0);
        }
        if (actA) {
            accA0 = __builtin_amdgcn_mfma_f32_32x32x16_bf16(vf00, pfA0, accA0, 0, 0, 0);
            accA0 = __builtin_amdgcn_mfma_f32_32x32x16_bf16(vf01, pfA1, accA0, 0, 0, 0);
            accA1 = __builtin_amdgcn_mfma_f32_32x32x16_bf16(vf10, pfA0, accA1, 0, 0, 0);
            accA1 = __builtin_amdgcn_mfma_f32_32x32x16_bf16(vf11, pfA1, accA1, 0, 0, 0);
        }
        __syncthreads();
    }
#undef QK_SM
#undef STAGE

    // ---- cross-wave combine: 3 partials per tile, stride-33 (conflict-free)
    lA += __shfl_xor(lA, 32);
    lB += __shfl_xor(lB, 32);
    float* cb = (float*)smem;
    float* sA = cb + lane * 33;            // tile A segment [64][33]
    float* sB = cb + (64 + lane) * 33;     // tile B segment [64][33]

    // R1: wave2 publishes both tile partials
    if (W == 2) {
        #pragma unroll
        for (int g = 0; g < 4; ++g) {
            *(f32x4*)(sA + 4 * g)      = f32x4{accA0[4*g+0], accA0[4*g+1], accA0[4*g+2], accA0[4*g+3]};
            *(f32x4*)(sA + 16 + 4 * g) = f32x4{accA1[4*g+0], accA1[4*g+1], accA1[4*g+2], accA1[4*g+3]};
            *(f32x4*)(sB + 4 * g)      = f32x4{accB0[4*g+0], accB0[4*g+1], accB0[4*g+2], accB0[4*g+3]};
            *(f32x4*)(sB + 16 + 4 * g) = f32x4{accB1[4*g+0], accB1[4*g+1], accB1[4*g+2], accB1[4*g+3]};
        }
        sA[32] = lA;  sB[32] = lB;
    }
    __syncthreads();
    if (W == 0) {
        #pragma unroll
        for (int g = 0; g < 4; ++g) {
            f32x4 u0 = *(f32x4*)(sA + 4 * g);
            f32x4 u1 = *(f32x4*)(sA + 16 + 4 * g);
            accA0[4*g+0] += u0[0]; accA0[4*g+1] += u0[1]; accA0[4*g+2] += u0[2]; accA0[4*g+3] += u0[3];
            accA1[4*g+0] += u1[0]; accA1[4*g+1] += u1[1]; accA1[4*g+2] += u1[2]; accA1[4*g+3] += u1[3];
        }
        lA += sA[32];
    }
    if (W == 1) {
        #pragma unroll
        for (int g = 0; g < 4; ++g) {
            f32x4 u0 = *(f32x4*)(sB + 4 * g);
            f32x4 u1 = *(f32x4*)(sB + 16 + 4 * g);
            accB0[4*g+0] += u0[0]; accB0[4*g+1] += u0[1]; accB0[4*g+2] += u0[2]; accB0[4*g+3] += u0[3];
            accB1[4*g+0] += u1[0]; accB1[4*g+1] += u1[1]; accB1[4*g+2] += u1[2]; accB1[4*g+3] += u1[3];
        }
        lB += sB[32];
    }
    __syncthreads();
    // R2: wave0 publishes its B partial, wave1 its A partial
    if (W == 0) {
        #pragma unroll
        for (int g = 0; g < 4; ++g) {
            *(f32x4*)(sB + 4 * g)      = f32x4{accB0[4*g+0], accB0[4*g+1], accB0[4*g+2], accB0[4*g+3]};
            *(f32x4*)(sB + 16 + 4 * g) = f32x4{accB1[4*g+0], accB1[4*g+1], accB1[4*g+2], accB1[4*g+3]};
        }
        sB[32] = lB;
    }
    if (W == 1) {
        #pragma unroll
        for (int g = 0; g < 4; ++g) {
            *(f32x4*)(sA + 4 * g)      = f32x4{accA0[4*g+0], accA0[4*g+1], accA0[4*g+2], accA0[4*g+3]};
            *(f32x4*)(sA + 16 + 4 * g) = f32x4{accA1[4*g+0], accA1[4*g+1], accA1[4*g+2], accA1[4*g+3]};
        }
        sA[32] = lA;
    }
    __syncthreads();
    if (W < 2) {
        f32x16 a0, a1;
        float lf;
        if (W == 0) {
            #pragma unroll
            for (int g = 0; g < 4; ++g) {
                f32x4 u0 = *(f32x4*)(sA + 4 * g);
                f32x4 u1 = *(f32x4*)(sA + 16 + 4 * g);
                accA0[4*g+0] += u0[0]; accA0[4*g+1] += u0[1]; accA0[4*g+2] += u0[2]; accA0[4*g+3] += u0[3];
                accA1[4*g+0] += u1[0]; accA1[4*g+1] += u1[1]; accA1[4*g+2] += u1[2]; accA1[4*g+3] += u1[3];
            }
            lf = lA + sA[32];
            a0 = accA0; a1 = accA1;
        } else {
            #pragma unroll
            for (int g = 0; g < 4; ++g) {
                f32x4 u0 = *(f32x4*)(sB + 4 * g);
                f32x4 u1 = *(f32x4*)(sB + 16 + 4 * g);
                accB0[4*g+0] += u0[0]; accB0[4*g+1] += u0[1]; accB0[4*g+2] += u0[2]; accB0[4*g+3] += u0[3];
                accB1[4*g+0] += u1[0]; accB1[4*g+1] += u1[1]; accB1[4*g+2] += u1[2]; accB1[4*g+3] += u1[3];
            }
            lf = lB + sB[32];
            a0 = accB0; a1 = accB1;
        }
        float rl = 1.0f / lf;
        int t0 = W ? t0B : t0A;
        int head = bh & 1, b = bh >> 1;
        float* hp = Hf + ((size_t)(b * T_SEQ) + t0 + ql) * 128 + head * 64 + 4 * h;
        #pragma unroll
        for (int g2 = 0; g2 < 4; ++g2) {
            f32x4 s0 = { a0[g2*4+0]*rl, a0[g2*4+1]*rl, a0[g2*4+2]*rl, a0[g2*4+3]*rl };
            *(f32x4*)(hp + 8 * g2) = s0;               // d = 8*g2+4h+0..3
            f32x4 s1 = { a1[g2*4+0]*rl, a1[g2*4+1]*rl, a1[g2*4+2]*rl, a1[g2*4+3]*rl };
            *(f32x4*)(hp + 32 + 8 * g2) = s1;          // d = 32+8*g2+4h+0..3
        }
    }
}

// ---------------------------------------------------------------------------
// Kernel 4a: one-shot Wout -> Wt bf16, transposed + xor-swizzled for LDS.
// ---------------------------------------------------------------------------
__global__ __launch_bounds__(256) void prep_wt(
    const float* __restrict__ Wout, short* __restrict__ Wt)
{
    int tid = blockIdx.x * 256 + threadIdx.x;   // 16384
    int j = tid >> 7, k = tid & 127;
    float v = Wout[k * 128 + j];
    int slot = k >> 3;
    Wt[j * 128 + (((slot ^ (j & 7)) << 3) | (k & 7))] = f2bfs(v);
}

// ---------------------------------------------------------------------------
// Kernel 4b: out = H(32768x128 f32, in d_out) @ Wout -> f32 (in place).
// Row-block-diagonal: each wave reads only its own 16 rows before writing.
// ---------------------------------------------------------------------------
__global__ __launch_bounds__(256) void out_proj(
    const float* Hf, const short* __restrict__ Wt, float* out)
{
    __shared__ __align__(16) char lws[32768];
    int tid = threadIdx.x;
    int w = tid >> 6, lane = tid & 63, c = lane & 15, g = lane >> 4;
    int cs = c & 7;
    #pragma unroll
    for (int z = 0; z < 8; ++z)
        __builtin_amdgcn_global_load_lds((gptr_t)(Wt + z * 2048 + w * 512 + lane * 8),
                                         (lptr_t)(lws + z * 4096 + w * 1024), 16, 0, 0);
    __syncthreads();

    int row0 = blockIdx.x * 64 + w * 16;
    bf16x8 af[4];
    const float* hp = Hf + (size_t)(row0 + c) * 128 + g * 8;
    #pragma unroll
    for (int kc = 0; kc < 4; ++kc) {
        f32x4 x0 = *(const f32x4*)(hp + kc * 32);
        f32x4 x1 = *(const f32x4*)(hp + kc * 32 + 4);
        u32x4 wv = { cvtpk(x0[0], x0[1]), cvtpk(x0[2], x0[3]),
                     cvtpk(x1[0], x1[1]), cvtpk(x1[2], x1[3]) };
        af[kc] = __builtin_bit_cast(bf16x8, wv);
    }
    #pragma unroll
    for (int jt = 0; jt < 8; ++jt) {
        f32x4 accum = {0.f, 0.f, 0.f, 0.f};
        #pragma unroll
        for (int kc = 0; kc < 4; ++kc) {
            int row = jt * 16 + c;
            bf16x8 bfr = *(const bf16x8*)(lws + row * 256 + (((kc * 4 + g) ^ cs) << 4));
            accum = __builtin_amdgcn_mfma_f32_16x16x32_bf16(af[kc], bfr, accum, 0, 0, 0);
        }
        #pragma unroll
        for (int r = 0; r < 4; ++r)
            out[(size_t)(row0 + g * 4 + r) * 128 + jt * 16 + c] = accum[r];
    }
}

// ---------------------------------------------------------------------------
extern "C" void kernel_launch(void* const* d_in, const int* in_sizes, int n_in,
                              void* d_out, int out_size, void* d_ws, size_t ws_size,
                              hipStream_t stream)
{
    (void)in_sizes; (void)n_in; (void)out_size; (void)ws_size;
    const float* x    = (const float*)d_in[0];
    const float* Wq1  = (const float*)d_in[1];
    const float* Wk1  = (const float*)d_in[2];
    const float* Wv1  = (const float*)d_in[3];
    const float* Wq2  = (const float*)d_in[4];
    const float* Wk2  = (const float*)d_in[5];
    const float* Wv2  = (const float*)d_in[6];
    const float* Wout = (const float*)d_in[7];
    float* out = (float*)d_out;

    char* ws = (char*)d_ws;
    short* Q  = (short*)(ws);                               // 8 MiB (dead after attn)
    short* K  = (short*)(ws + (size_t)8  * 1024 * 1024);    // 8 MiB
    short* Vt = (short*)(ws + (size_t)16 * 1024 * 1024);    // 8 MiB
    short* Wt = Q;                                          // reuse Q region
    float* Hf = out;                                        // f32 H lives in d_out

    qk_proj <<<8192, 256, 0, stream>>>(x, Wq1, Wk1, Wq2, Wk2, Q, K);
    v_proj_t<<<1024, 256, 0, stream>>>(x, Wv1, Wv2, Vt);
    attn    <<<1024, 192, 0, stream>>>(Q, K, Vt, Hf);
    prep_wt <<<  64, 256, 0, stream>>>(Wout, Wt);
    out_proj<<< 512, 256, 0, stream>>>(Hf, Wt, out);
}

// Round 2
// 105.713 us; speedup vs baseline: 1.4708x; 1.4708x over previous
//
#include <hip/hip_runtime.h>
#include <hip/hip_bf16.h>
#include <stdint.h>

#define T_SEQ 4096

typedef float  f32x4   __attribute__((ext_vector_type(4)));
typedef float  f32x16  __attribute__((ext_vector_type(16)));
typedef short  bf16x8  __attribute__((ext_vector_type(8)));
typedef unsigned int u32x4 __attribute__((ext_vector_type(4)));

typedef const __attribute__((address_space(1))) uint32_t* gptr_t;
typedef __attribute__((address_space(3))) uint32_t* lptr_t;

__device__ __forceinline__ uint32_t f2bf1(float f) {
    uint32_t u = __float_as_uint(f);
    return (u + 0x7fffu + ((u >> 16) & 1u)) >> 16;   // RNE f32->bf16
}
__device__ __forceinline__ short f2bfs(float f) { return (short)f2bf1(f); }
__device__ __forceinline__ uint32_t cvtpk(float lo, float hi) {
    uint32_t r;
    asm("v_cvt_pk_bf16_f32 %0, %1, %2" : "=v"(r) : "v"(lo), "v"(hi));
    return r;
}

// ---------------------------------------------------------------------------
// Kernel 1: Q,K projections. Q pre-scaled by 0.125*log2(e) (softmax uses 2^x).
// Layout: [bh=b*2+h][t][64] bf16.
// ---------------------------------------------------------------------------
__global__ __launch_bounds__(256) void qk_proj(
    const float* __restrict__ x,
    const float* __restrict__ Wq1, const float* __restrict__ Wk1,
    const float* __restrict__ Wq2, const float* __restrict__ Wk2,
    short* __restrict__ Q, short* __restrict__ K)
{
    int idx = blockIdx.x * 256 + threadIdx.x;
    int d = idx & 63;
    int t = (idx >> 6) & (T_SEQ - 1);
    int b = idx >> 18;
    const float* xp = x + (size_t)(b * T_SEQ + t) * 6;
    float x0 = xp[0], x1 = xp[1], x2 = xp[2];
    float x3 = xp[3], x4 = xp[4], x5 = xp[5];
    const float QS = 0.125f * 1.44269504088896340736f;
    float q1 = (x0 * Wq1[d] + x1 * Wq1[64 + d] + x2 * Wq1[128 + d]) * QS;
    float k1 =  x0 * Wk1[d] + x1 * Wk1[64 + d] + x2 * Wk1[128 + d];
    float q2 = (x3 * Wq2[d] + x4 * Wq2[64 + d] + x5 * Wq2[128 + d]) * QS;
    float k2 =  x3 * Wk2[d] + x4 * Wk2[64 + d] + x5 * Wk2[128 + d];
    size_t base1 = ((size_t)(b * 2 + 0) * T_SEQ + t) * 64 + d;
    size_t base2 = ((size_t)(b * 2 + 1) * T_SEQ + t) * 64 + d;
    Q[base1] = f2bfs(q1);  Q[base2] = f2bfs(q2);
    K[base1] = f2bfs(k1);  K[base2] = f2bfs(k2);
}

// ---------------------------------------------------------------------------
// Kernel 2: V projection written TRANSPOSED: Vt[bh][d][t] bf16.
// ---------------------------------------------------------------------------
__global__ __launch_bounds__(256) void v_proj_t(
    const float* __restrict__ x,
    const float* __restrict__ Wv1, const float* __restrict__ Wv2,
    short* __restrict__ Vt)
{
    int bh = blockIdx.x >> 6;
    int tt = blockIdx.x & 63;
    int head = bh & 1, b = bh >> 1;
    int t  = tt * 64 + (threadIdx.x & 63);
    int dg = threadIdx.x >> 6;
    const float* Wv = head ? Wv2 : Wv1;
    const float* xp = x + (size_t)(b * T_SEQ + t) * 6 + head * 3;
    float x0 = xp[0], x1 = xp[1], x2 = xp[2];
    size_t base = (size_t)bh * 64 * T_SEQ + t;
    #pragma unroll
    for (int k = 0; k < 16; ++k) {
        int d = dg * 16 + k;
        float v = x0 * Wv[d] + x1 * Wv[64 + d] + x2 * Wv[128 + d];
        Vt[base + (size_t)d * T_SEQ] = f2bfs(v);
    }
}

// ---------------------------------------------------------------------------
// Kernel 3: causal flash attention, FOLDED, BARRIER-FREE main loop.
//   2 waves/block, fold pair (A=i, B=127-i), chunk = 64 kv, wave W owns
//   kv-half [kv0+32W, +31] for both tiles (as in the 72.6us R0 kernel), BUT:
//   - K staging is PER-WAVE OWNED: wave W global_load_lds's its own 32 kv
//     rows into its private 4KB LDS region (dbuf x2, 16KB total K LDS).
//     No cross-wave LDS dependency -> NO __syncthreads in the loop.
//   - V fragments are register-prefetched TWO chunks ahead from global
//     (fixes R1: V latency fully hidden under a whole chunk of compute).
//   - Per-iteration sync is a single counted `s_waitcnt vmcnt(8)`: every
//     body issues exactly 8 loads (4 V + 4 K-stage; ghost chunks past sweep
//     are address-clamped so the count stays uniform), so vmcnt(8) retires
//     exactly chunk c's loads while c+1/c+2 prefetch stays in flight.
//   - Loop unrolled x2 so vf double-buffer regs are statically indexed.
//   MASK RULE: mask needed iff max_kv (kv0+32W+31) > MIN q of tile (t0X).
//   Combine: unchanged R0 cross-wave LDS combine; its __syncthreads provides
//   the vmcnt drain before smem is reused as the combine buffer.
// ---------------------------------------------------------------------------
__global__ __launch_bounds__(128, 2) void attn(
    const short* __restrict__ Q, const short* __restrict__ K,
    const short* __restrict__ Vt, float* __restrict__ Hf)
{
    __shared__ __align__(16) char smem[19456];  // 16KB K dbuf; combine reuses

    int id = blockIdx.x;
    int xcd = id & 7, j = id >> 3;       // j 0..127
    int bh = xcd * 2 + (j & 1);          // 2 bh per XCD (L2 locality)
    int i  = j >> 1;                     // fold index 0..63
    int tid = threadIdx.x;
    int W = tid >> 6;                    // wave = kv-half
    int lane = tid & 63;
    int ql = lane & 31, h = lane >> 5;
    int t0A = 32 * i, t0B = 32 * (127 - i);
    int qA = t0A + ql, qB = t0B + ql;
    int sweep = ((127 - i) >> 1) + 1;    // chunks (tile B extent), 33..64

    size_t kvbase = (size_t)bh * (T_SEQ * 64);

    // Q fragments for both tiles (B-operand): lane holds Q[q][ks*16+h*8+j]
    bf16x8 qfA[4], qfB[4];
    #pragma unroll
    for (int ks = 0; ks < 4; ++ks) {
        qfA[ks] = *(const bf16x8*)(Q + kvbase + (size_t)qA * 64 + ks * 16 + h * 8);
        qfB[ks] = *(const bf16x8*)(Q + kvbase + (size_t)qB * 64 + ks * 16 + h * 8);
    }

    // Per-wave K staging: 64 lanes cover 8 rows x 128B per instr, 4 instrs =
    // this wave's 32 kv rows. Pre-swizzled source column, LDS dest linear.
    int r8 = lane >> 3;                  // 0..7 (row within 8-row group)
    int scol = ((lane & 7) ^ r8) * 8;
    const short* ksrc0 = K + kvbase + scol;

    // V direct-from-global row pointers (d = ql and d = 32+ql)
    const short* vrow0 = Vt + kvbase + (size_t)ql * T_SEQ;
    const short* vrow1 = vrow0 + (size_t)32 * T_SEQ;

    f32x16 accA0, accA1, accB0, accB1;
    #pragma unroll
    for (int r = 0; r < 16; ++r) { accA0[r]=0.f; accA1[r]=0.f; accB0[r]=0.f; accB1[r]=0.f; }
    float lA = 0.f, lB = 0.f;
    int swz = (ql & 7) << 4;

#define STAGEK(bsel, kvv)                                                       \
    {                                                                           \
        char* kb = smem + (bsel) * 8192 + W * 4096;                             \
        _Pragma("unroll")                                                       \
        for (int z = 0; z < 4; ++z) {                                           \
            int srow = (kvv) + 32 * W + z * 8 + r8;                             \
            srow = srow > (T_SEQ - 1) ? (T_SEQ - 1) : srow;                     \
            __builtin_amdgcn_global_load_lds(                                   \
                (gptr_t)(ksrc0 + (size_t)srow * 64),                            \
                (lptr_t)(kb + z * 1024), 16, 0, 0);                             \
        }                                                                       \
    }

#define VISSUE(v0, v1, v2, v3, kvv)                                             \
    {                                                                           \
        int kvw = (kvv) + 32 * W + 8 * h;                                       \
        int kvc = kvw > (T_SEQ - 24) ? (T_SEQ - 24) : kvw;                      \
        v0 = *(const bf16x8*)(vrow0 + kvc);                                     \
        v1 = *(const bf16x8*)(vrow0 + kvc + 16);                                \
        v2 = *(const bf16x8*)(vrow1 + kvc);                                     \
        v3 = *(const bf16x8*)(vrow1 + kvc + 16);                                \
    }

#define QK_SM(qfX, qX, lX, pf0, pf1)                                            \
        {                                                                       \
            f32x16 Sv;                                                          \
            _Pragma("unroll") for (int r = 0; r < 16; ++r) Sv[r] = 0.f;         \
            Sv = __builtin_amdgcn_mfma_f32_32x32x16_bf16(kf0, qfX[0], Sv,0,0,0);\
            Sv = __builtin_amdgcn_mfma_f32_32x32x16_bf16(kf1, qfX[1], Sv,0,0,0);\
            Sv = __builtin_amdgcn_mfma_f32_32x32x16_bf16(kf2, qfX[2], Sv,0,0,0);\
            Sv = __builtin_amdgcn_mfma_f32_32x32x16_bf16(kf3, qfX[3], Sv,0,0,0);\
            bool needmask = (kv0 + 32 * W + 31 > (qX) - ql);  /* max_kv>t0X */  \
            uint32_t pw[8];                                                     \
            float l0 = 0.f, l1 = 0.f;                                           \
            _Pragma("unroll") for (int e = 0; e < 8; ++e) {                     \
                float p0 = __builtin_amdgcn_exp2f(Sv[2 * e]);                   \
                float p1 = __builtin_amdgcn_exp2f(Sv[2 * e + 1]);               \
                if (needmask) {                                                 \
                    int kv = kv0 + 32 * W + 4 * h + 2 * (e & 1) + 8 * (e >> 1); \
                    p0 = (kv     <= (qX)) ? p0 : 0.f;                           \
                    p1 = (kv + 1 <= (qX)) ? p1 : 0.f;                           \
                }                                                               \
                l0 += p0; l1 += p1;                                             \
                pw[e] = cvtpk(p0, p1);                                          \
            }                                                                   \
            lX += l0 + l1;                                                      \
            {                                                                   \
                uint32_t a0 = pw[0], b0 = pw[2], a1 = pw[1], b1 = pw[3];        \
                asm("v_permlane32_swap_b32 %0, %1" : "+v"(a0), "+v"(b0));       \
                asm("v_permlane32_swap_b32 %0, %1" : "+v"(a1), "+v"(b1));       \
                u32x4 fr = {a0, a1, b0, b1};                                    \
                pf0 = __builtin_bit_cast(bf16x8, fr);                           \
                uint32_t c0 = pw[4], d0 = pw[6], c1 = pw[5], d1 = pw[7];        \
                asm("v_permlane32_swap_b32 %0, %1" : "+v"(c0), "+v"(d0));       \
                asm("v_permlane32_swap_b32 %0, %1" : "+v"(c1), "+v"(d1));       \
                u32x4 fr1 = {c0, c1, d0, d1};                                   \
                pf1 = __builtin_bit_cast(bf16x8, fr1);                          \
            }                                                                   \
        }

#define BODY(cc, v0, v1, v2, v3)                                                \
    {                                                                           \
        const int kv0 = (cc) * 64;                                              \
        asm volatile("s_waitcnt vmcnt(8)" ::: "memory");                        \
        const char* krow = smem + ((cc) & 1) * 8192 + W * 4096 + ql * 128;      \
        bf16x8 kf0 = *(const bf16x8*)(krow + ((0 * 32 + h * 16) ^ swz));        \
        bf16x8 kf1 = *(const bf16x8*)(krow + ((1 * 32 + h * 16) ^ swz));        \
        bf16x8 kf2 = *(const bf16x8*)(krow + ((2 * 32 + h * 16) ^ swz));        \
        bf16x8 kf3 = *(const bf16x8*)(krow + ((3 * 32 + h * 16) ^ swz));        \
        bool actA = (kv0 + 32 * W <= t0A + 31);                                 \
        bool actB = (kv0 + 32 * W <= t0B + 31);                                 \
        bf16x8 pfA0, pfA1, pfB0, pfB1;                                          \
        __builtin_amdgcn_s_setprio(1);                                          \
        if (actB) QK_SM(qfB, qB, lB, pfB0, pfB1)                                \
        if (actA) QK_SM(qfA, qA, lA, pfA0, pfA1)                                \
        if (actB) {                                                             \
            accB0 = __builtin_amdgcn_mfma_f32_32x32x16_bf16(v0, pfB0, accB0, 0, 0, 0); \
            accB0 = __builtin_amdgcn_mfma_f32_32x32x16_bf16(v1, pfB1, accB0, 0, 0, 0); \
            accB1 = __builtin_amdgcn_mfma_f32_32x32x16_bf16(v2, pfB0, accB1, 0, 0, 0); \
            accB1 = __builtin_amdgcn_mfma_f32_32x32x16_bf16(v3, pfB1, accB1, 0, 0, 0); \
        }                                                                       \
        if (actA) {                                                             \
            accA0 = __builtin_amdgcn_mfma_f32_32x32x16_bf16(v0, pfA0, accA0, 0, 0, 0); \
            accA0 = __builtin_amdgcn_mfma_f32_32x32x16_bf16(v1, pfA1, accA0, 0, 0, 0); \
            accA1 = __builtin_amdgcn_mfma_f32_32x32x16_bf16(v2, pfA0, accA1, 0, 0, 0); \
            accA1 = __builtin_amdgcn_mfma_f32_32x32x16_bf16(v3, pfA1, accA1, 0, 0, 0); \
        }                                                                       \
        __builtin_amdgcn_s_setprio(0);                                          \
        VISSUE(v0, v1, v2, v3, kv0 + 128);                                      \
        STAGEK((cc) & 1, kv0 + 128);                                            \
    }

    // Prologue: depth-2 prefetch (V->regs, K->per-wave LDS). 16 outstanding.
    bf16x8 vfA0, vfA1, vfA2, vfA3, vfB0, vfB1, vfB2, vfB3;
    VISSUE(vfA0, vfA1, vfA2, vfA3, 0);
    STAGEK(0, 0);
    VISSUE(vfB0, vfB1, vfB2, vfB3, 64);
    STAGEK(1, 64);

    int c = 0;
    for (;;) {
        BODY(c, vfA0, vfA1, vfA2, vfA3);
        if (++c >= sweep) break;
        BODY(c, vfB0, vfB1, vfB2, vfB3);
        if (++c >= sweep) break;
    }
#undef BODY
#undef QK_SM
#undef VISSUE
#undef STAGEK

    // ---- cross-wave combine: wave0 finalizes tile A, wave1 tile B ----
    // The barrier's implicit vmcnt(0)+lgkmcnt(0) drain covers the in-flight
    // ghost prefetches before smem is reused as the combine buffer.
    __syncthreads();
    lA += __shfl_xor(lA, 32);
    lB += __shfl_xor(lB, 32);
    float* cbuf = (float*)smem;          // [2 tiles][64 lanes][36 f32]
    float* lbuf = cbuf + 4608;           // [2][64]
    if (W == 0) {                        // write MY tile-B partial to slot 1
        float* pb = cbuf + 2304 + lane * 36;
        #pragma unroll
        for (int g2 = 0; g2 < 4; ++g2) {
            *(f32x4*)(pb + g2 * 4)      = f32x4{accB0[g2*4+0], accB0[g2*4+1], accB0[g2*4+2], accB0[g2*4+3]};
            *(f32x4*)(pb + 16 + g2 * 4) = f32x4{accB1[g2*4+0], accB1[g2*4+1], accB1[g2*4+2], accB1[g2*4+3]};
        }
        lbuf[64 + lane] = lB;
    } else {                             // write MY tile-A partial to slot 0
        float* pb = cbuf + lane * 36;
        #pragma unroll
        for (int g2 = 0; g2 < 4; ++g2) {
            *(f32x4*)(pb + g2 * 4)      = f32x4{accA0[g2*4+0], accA0[g2*4+1], accA0[g2*4+2], accA0[g2*4+3]};
            *(f32x4*)(pb + 16 + g2 * 4) = f32x4{accA1[g2*4+0], accA1[g2*4+1], accA1[g2*4+2], accA1[g2*4+3]};
        }
        lbuf[lane] = lA;
    }
    __syncthreads();
    {
        float* pb = cbuf + W * 2304 + lane * 36;
        float lf = (W ? lB : lA) + lbuf[W * 64 + lane];
        float rl = 1.0f / lf;
        int t0 = W ? t0B : t0A;
        f32x16 a0 = W ? accB0 : accA0;
        f32x16 a1 = W ? accB1 : accA1;
        int head = bh & 1, b = bh >> 1;
        float* hp = Hf + ((size_t)(b * T_SEQ) + t0 + ql) * 128 + head * 64 + 4 * h;
        #pragma unroll
        for (int g2 = 0; g2 < 4; ++g2) {
            f32x4 o0 = *(f32x4*)(pb + g2 * 4);
            f32x4 o1 = *(f32x4*)(pb + 16 + g2 * 4);
            f32x4 s0 = { (a0[g2*4+0]+o0[0])*rl, (a0[g2*4+1]+o0[1])*rl,
                         (a0[g2*4+2]+o0[2])*rl, (a0[g2*4+3]+o0[3])*rl };
            *(f32x4*)(hp + 8 * g2) = s0;               // d = 8*g2+4h+0..3
            f32x4 s1 = { (a1[g2*4+0]+o1[0])*rl, (a1[g2*4+1]+o1[1])*rl,
                         (a1[g2*4+2]+o1[2])*rl, (a1[g2*4+3]+o1[3])*rl };
            *(f32x4*)(hp + 32 + 8 * g2) = s1;          // d = 32+8*g2+4h+0..3
        }
    }
}

// ---------------------------------------------------------------------------
// Kernel 4a: one-shot Wout -> Wt bf16, transposed + xor-swizzled for LDS.
// ---------------------------------------------------------------------------
__global__ __launch_bounds__(256) void prep_wt(
    const float* __restrict__ Wout, short* __restrict__ Wt)
{
    int tid = blockIdx.x * 256 + threadIdx.x;   // 16384
    int j = tid >> 7, k = tid & 127;
    float v = Wout[k * 128 + j];
    int slot = k >> 3;
    Wt[j * 128 + (((slot ^ (j & 7)) << 3) | (k & 7))] = f2bfs(v);
}

// ---------------------------------------------------------------------------
// Kernel 4b: out = H(32768x128 f32, in d_out) @ Wout -> f32 (in place).
// Row-block-diagonal: each wave reads only its own 16 rows before writing.
// ---------------------------------------------------------------------------
__global__ __launch_bounds__(256) void out_proj(
    const float* Hf, const short* __restrict__ Wt, float* out)
{
    __shared__ __align__(16) char lws[32768];
    int tid = threadIdx.x;
    int w = tid >> 6, lane = tid & 63, c = lane & 15, g = lane >> 4;
    int cs = c & 7;
    #pragma unroll
    for (int z = 0; z < 8; ++z)
        __builtin_amdgcn_global_load_lds((gptr_t)(Wt + z * 2048 + w * 512 + lane * 8),
                                         (lptr_t)(lws + z * 4096 + w * 1024), 16, 0, 0);
    __syncthreads();

    int row0 = blockIdx.x * 64 + w * 16;
    bf16x8 af[4];
    const float* hp = Hf + (size_t)(row0 + c) * 128 + g * 8;
    #pragma unroll
    for (int kc = 0; kc < 4; ++kc) {
        f32x4 x0 = *(const f32x4*)(hp + kc * 32);
        f32x4 x1 = *(const f32x4*)(hp + kc * 32 + 4);
        u32x4 wv = { cvtpk(x0[0], x0[1]), cvtpk(x0[2], x0[3]),
                     cvtpk(x1[0], x1[1]), cvtpk(x1[2], x1[3]) };
        af[kc] = __builtin_bit_cast(bf16x8, wv);
    }
    #pragma unroll
    for (int jt = 0; jt < 8; ++jt) {
        f32x4 accum = {0.f, 0.f, 0.f, 0.f};
        #pragma unroll
        for (int kc = 0; kc < 4; ++kc) {
            int row = jt * 16 + c;
            bf16x8 bfr = *(const bf16x8*)(lws + row * 256 + (((kc * 4 + g) ^ cs) << 4));
            accum = __builtin_amdgcn_mfma_f32_16x16x32_bf16(af[kc], bfr, accum, 0, 0, 0);
        }
        #pragma unroll
        for (int r = 0; r < 4; ++r)
            out[(size_t)(row0 + g * 4 + r) * 128 + jt * 16 + c] = accum[r];
    }
}

// ---------------------------------------------------------------------------
extern "C" void kernel_launch(void* const* d_in, const int* in_sizes, int n_in,
                              void* d_out, int out_size, void* d_ws, size_t ws_size,
                              hipStream_t stream)
{
    (void)in_sizes; (void)n_in; (void)out_size; (void)ws_size;
    const float* x    = (const float*)d_in[0];
    const float* Wq1  = (const float*)d_in[1];
    const float* Wk1  = (const float*)d_in[2];
    const float* Wv1  = (const float*)d_in[3];
    const float* Wq2  = (const float*)d_in[4];
    const float* Wk2  = (const float*)d_in[5];
    const float* Wv2  = (const float*)d_in[6];
    const float* Wout = (const float*)d_in[7];
    float* out = (float*)d_out;

    char* ws = (char*)d_ws;
    short* Q  = (short*)(ws);                               // 8 MiB (dead after attn)
    short* K  = (short*)(ws + (size_t)8  * 1024 * 1024);    // 8 MiB
    short* Vt = (short*)(ws + (size_t)16 * 1024 * 1024);    // 8 MiB
    short* Wt = Q;                                          // reuse Q region
    float* Hf = out;                                        // f32 H lives in d_out

    qk_proj <<<8192, 256, 0, stream>>>(x, Wq1, Wk1, Wq2, Wk2, Q, K);
    v_proj_t<<<1024, 256, 0, stream>>>(x, Wv1, Wv2, Vt);
    attn    <<<1024, 128, 0, stream>>>(Q, K, Vt, Hf);
    prep_wt <<<  64, 256, 0, stream>>>(Wout, Wt);
    out_proj<<< 512, 256, 0, stream>>>(Hf, Wt, out);
}